// Round 3
// baseline (325.297 us; speedup 1.0000x reference)
//
#include <hip/hip_runtime.h>

#define B_   8
#define N_   1024
#define D_   512
#define H_   8
#define DH_  64
#define SCALE_ 0.044194173824159216f   // 1/sqrt(512)
#define LOG2E_ 1.4426950408889634f

typedef __attribute__((ext_vector_type(8))) short bf16x8;
typedef __attribute__((ext_vector_type(4))) float f32x4;
typedef __attribute__((ext_vector_type(8))) unsigned short us8;
typedef __attribute__((ext_vector_type(4))) unsigned int u32x4;

__device__ __forceinline__ unsigned short f2bf(float f) {
  unsigned u = __builtin_bit_cast(unsigned, f);
  u += 0x7fffu + ((u >> 16) & 1u);           // RNE
  return (unsigned short)(u >> 16);
}
__device__ __forceinline__ float bf2f(unsigned short h) {
  unsigned u = ((unsigned)h) << 16;
  return __builtin_bit_cast(float, u);
}
__device__ __forceinline__ void gl_lds16(const void* g, void* l) {
  __builtin_amdgcn_global_load_lds(
      (const __attribute__((address_space(1))) unsigned int*)g,
      (__attribute__((address_space(3))) unsigned int*)l, 16, 0, 0);
}
__device__ __forceinline__ unsigned cvt_pk_bf16(float lo, float hi) {
  unsigned r;
  asm("v_cvt_pk_bf16_f32 %0, %1, %2" : "=v"(r) : "v"(lo), "v"(hi));
  return r;
}
#define MFMA16(a, b, c) __builtin_amdgcn_mfma_f32_16x16x32_bf16((a), (b), (c), 0, 0, 0)

// ---------------------------------------------------------------------------
// prep: WT_swz[mat][n][kmap] = bf16(W[k][n]); kmap XOR-swizzled so that a
// LINEAR global_load_lds copy + XOR on the ds_read side is bank-conflict-free.
// ---------------------------------------------------------------------------
__global__ void prep_w(const float* __restrict__ Wq, const float* __restrict__ Wk,
                       const float* __restrict__ Wv, const float* __restrict__ Wo,
                       unsigned short* __restrict__ WT) {
  int idx = blockIdx.x * 256 + threadIdx.x;          // 4 * 512 * 512 total
  int mat = idx >> 18;
  int rem = idx & 0x3FFFF;
  int k = rem >> 9, n = rem & 511;
  const float* W = (mat == 0) ? Wq : (mat == 1) ? Wk : (mat == 2) ? Wv : Wo;
  float v = W[(size_t)k * 512 + n];
  int kmap = (k & ~63) | ((k & 63) ^ ((n & 7) << 3));
  WT[(size_t)mat * 262144 + (size_t)n * 512 + kmap] = f2bf(v);
}

// ---------------------------------------------------------------------------
// GEMM core body (128x128 tile, BK=64, 4 waves 2x2, wave = 64x64 out)
// ---------------------------------------------------------------------------
#define GEMM_BODY(A, W, bias, EPILOGUE)                                          \
  __shared__ unsigned short Alds[2][128][72];                                    \
  __shared__ unsigned short Blds[2][128 * 64];                                   \
  const int t = threadIdx.x, w = t >> 6, l = t & 63;                             \
  const int wr = w >> 1, wc = w & 1;                                             \
  const int lm = l & 15, lg = l >> 4;                                            \
  const int bm = blockIdx.x >> 2, bn = blockIdx.x & 3;                           \
  f32x4 acc[4][4];                                                               \
  _Pragma("unroll") for (int mt = 0; mt < 4; ++mt)                               \
  _Pragma("unroll") for (int nt = 0; nt < 4; ++nt)                               \
      acc[mt][nt] = f32x4{0.f, 0.f, 0.f, 0.f};                                   \
  float4 areg[8];                                                                \
  auto loadA = [&](int kt) {                                                     \
    _Pragma("unroll") for (int p = 0; p < 8; ++p) {                              \
      int row = (t >> 4) + p * 16, col = (t & 15) * 4;                           \
      areg[p] = *(const float4*)&A[((size_t)(bm * 128 + row)) * 512 + kt * 64 + col]; \
    }                                                                            \
  };                                                                             \
  auto issueB = [&](int kt, int sb) {                                            \
    _Pragma("unroll") for (int p = 0; p < 4; ++p) {                              \
      int chunk = w * 4 + p;                                                     \
      int row = chunk * 8 + (l >> 3), gc = kt * 64 + (l & 7) * 8;                \
      gl_lds16(&W[((size_t)(bn * 128 + row)) * 512 + gc],                        \
               &Blds[sb][chunk * 512 + l * 8]);                                  \
    }                                                                            \
  };                                                                             \
  auto writeA = [&](int sb) {                                                    \
    _Pragma("unroll") for (int p = 0; p < 8; ++p) {                              \
      int row = (t >> 4) + p * 16, col = (t & 15) * 4;                           \
      float4 v = areg[p];                                                        \
      uint2 d;                                                                   \
      d.x = (unsigned)f2bf(v.x) | ((unsigned)f2bf(v.y) << 16);                   \
      d.y = (unsigned)f2bf(v.z) | ((unsigned)f2bf(v.w) << 16);                   \
      *(uint2*)&Alds[sb][row][col] = d;                                          \
    }                                                                            \
  };                                                                             \
  loadA(0); issueB(0, 0); writeA(0);                                             \
  __syncthreads();                                                               \
  int buf = 0;                                                                   \
  for (int kt = 0; kt < 8; ++kt) {                                               \
    if (kt + 1 < 8) { loadA(kt + 1); issueB(kt + 1, buf ^ 1); }                  \
    _Pragma("unroll") for (int kk = 0; kk < 2; ++kk) {                           \
      bf16x8 af[4], bfv[4];                                                      \
      _Pragma("unroll") for (int mt = 0; mt < 4; ++mt)                           \
        af[mt] = *(const bf16x8*)&Alds[buf][wr * 64 + mt * 16 + lm][kk * 32 + lg * 8]; \
      _Pragma("unroll") for (int nt = 0; nt < 4; ++nt) {                         \
        int rr = wc * 64 + nt * 16 + lm;                                         \
        int c = (kk * 32 + lg * 8) ^ ((rr & 7) << 3);                            \
        bfv[nt] = *(const bf16x8*)&Blds[buf][rr * 64 + c];                       \
      }                                                                          \
      _Pragma("unroll") for (int mt = 0; mt < 4; ++mt)                           \
      _Pragma("unroll") for (int nt = 0; nt < 4; ++nt)                           \
          acc[mt][nt] = MFMA16(af[mt], bfv[nt], acc[mt][nt]);                    \
    }                                                                            \
    if (kt + 1 < 8) writeA(buf ^ 1);                                             \
    __syncthreads();                                                             \
    buf ^= 1;                                                                    \
  }                                                                              \
  _Pragma("unroll") for (int mt = 0; mt < 4; ++mt)                               \
  _Pragma("unroll") for (int nt = 0; nt < 4; ++nt) {                             \
    int gn = bn * 128 + wc * 64 + nt * 16 + lm;                                  \
    float bv_ = bias[gn];                                                        \
    _Pragma("unroll") for (int e = 0; e < 4; ++e) {                              \
      int gm = bm * 128 + wr * 64 + mt * 16 + lg * 4 + e;                        \
      float v = acc[mt][nt][e] + bv_;                                            \
      size_t off = (size_t)gm * 512 + gn;                                        \
      EPILOGUE                                                                   \
    }                                                                            \
  }

// fused 3 projection GEMMs: blockIdx.y = {0:Q->qb, 1:K->kb, 2:K->vtmp}
__global__ __launch_bounds__(256, 2) void gemm_proj3(
    const float* __restrict__ Q, const float* __restrict__ K,
    const unsigned short* __restrict__ WT,
    const float* __restrict__ bq, const float* __restrict__ bk,
    const float* __restrict__ bv, const float* __restrict__ mask,
    unsigned short* __restrict__ qb, unsigned short* __restrict__ kb,
    unsigned short* __restrict__ vtmp) {
  const int mat = blockIdx.y;
  const float* A = (mat == 0) ? Q : K;
  const unsigned short* W = WT + (size_t)mat * 262144;
  const float* bias = (mat == 0) ? bq : (mat == 1) ? bk : bv;
  unsigned short* outp = (mat == 0) ? qb : (mat == 1) ? kb : vtmp;
  GEMM_BODY(A, W, bias, { outp[off] = f2bf(v * mask[gm]); })
}

// final GEMM: out_f32 = resid + relu(acc + bias) * mask
__global__ __launch_bounds__(256, 2) void gemm_final(
    const float* __restrict__ A, const unsigned short* __restrict__ W,
    const float* __restrict__ bias, const float* __restrict__ mask,
    const float* __restrict__ resid, float* __restrict__ outp) {
  GEMM_BODY(A, W, bias, { outp[off] = resid[off] + fmaxf(v, 0.f) * mask[gm]; })
}

// ---------------------------------------------------------------------------
// v transpose: vtmp[b][n][d] (bf16) -> vT[b][d][n] (bf16)
// ---------------------------------------------------------------------------
__global__ void vtrans_kernel(const unsigned short* __restrict__ vtmp,
                              unsigned short* __restrict__ vT) {
  __shared__ unsigned short T[64][72];
  int b = blockIdx.x, ntile = blockIdx.y, dtile = blockIdx.z;
  int n0 = ntile * 64, d0 = dtile * 64;
  int t = threadIdx.x;
#pragma unroll
  for (int p = 0; p < 2; ++p) {
    int r = (t >> 3) + p * 32;
    int c = (t & 7) * 8;
    *(us8*)&T[r][c] = *(const us8*)&vtmp[((size_t)(b * N_ + n0 + r)) * D_ + d0 + c];
  }
  __syncthreads();
#pragma unroll
  for (int p = 0; p < 2; ++p) {
    int r = (t >> 3) + p * 32;   // d-local
    int c = (t & 7) * 8;         // n-local
    us8 v;
#pragma unroll
    for (int e = 0; e < 8; ++e) v[e] = T[c + e][r];
    *(us8*)&vT[((size_t)(b * D_ + d0 + r)) * N_ + n0 + c] = v;
  }
}

// ---------------------------------------------------------------------------
// attention, barrier-free: block = (h, i-tile of 16 rows), 8 waves = 8 b.
// Each wave fully independent: per-lane direct U loads (L1/L2 absorb the
// b/j intra-line reuse), reg-prefetch (A/B sets) one j-tile ahead,
// per-wave Plds for the P D->A relayout. No __syncthreads anywhere.
// ---------------------------------------------------------------------------
__global__ __launch_bounds__(512, 2) void attn_kernel(
    const unsigned short* __restrict__ qb, const unsigned short* __restrict__ kb,
    const unsigned short* __restrict__ vT, const float* __restrict__ U,
    const float* __restrict__ mask, float* __restrict__ O32) {
  __shared__ float Plds[8][16 * 36];     // 18.4 KB -> 2 blocks/CU
  const int t = threadIdx.x, w = t >> 6, l = t & 63;
  int bid = (int)blockIdx.x;
  bid = (bid & 7) * 64 + (bid >> 3);     // XCD swizzle: 64 consecutive tiles (one h) per XCD
  const int h = bid >> 6;
  const int i0 = (bid & 63) * 16;
  const int b = w;
  const int lm = l & 15, lg = l >> 4;

  // per-lane bases
  const float* Ub = U + (((size_t)h * N_ + i0 + lg * 4) * N_ + lm) * B_ + b;
  const unsigned short* Kb = kb + (size_t)b * N_ * D_ + h * DH_ + lg * 8;
  const unsigned short* Vb = vT + ((size_t)b * D_ + h * DH_ + lm) * N_ + lg * 8;
  const float* Mb = mask + b * N_ + lm;

  // Q fragments (A-layout), resident for the whole block
  bf16x8 qf[2];
#pragma unroll
  for (int kt = 0; kt < 2; ++kt)
    qf[kt] = *(const bf16x8*)&qb[((size_t)b * N_ + i0 + lm) * D_ + h * DH_ + kt * 32 + lg * 8];

  f32x4 acc[4];
#pragma unroll
  for (int nt = 0; nt < 4; ++nt) acc[nt] = f32x4{0.f, 0.f, 0.f, 0.f};
  float lrun[4] = {0.f, 0.f, 0.f, 0.f};

  float uA[8], uB[8];
  bf16x8 kA[2][2], kB[2][2], vA[4], vB[4];
  float mAv[2], mBv[2];

  auto pref = [&](int jt, float (&u)[8], bf16x8 (&kf)[2][2], bf16x8 (&vf)[4],
                  float (&mj)[2]) {
#pragma unroll
    for (int e = 0; e < 4; ++e) {
      u[e * 2]     = Ub[(size_t)e * 8192 + jt * 256];
      u[e * 2 + 1] = Ub[(size_t)e * 8192 + jt * 256 + 128];
    }
#pragma unroll
    for (int j2 = 0; j2 < 2; ++j2)
#pragma unroll
      for (int kt = 0; kt < 2; ++kt)
        kf[j2][kt] = *(const bf16x8*)&Kb[(size_t)(jt * 32 + j2 * 16 + lm) * D_ + kt * 32];
#pragma unroll
    for (int nt = 0; nt < 4; ++nt)
      vf[nt] = *(const bf16x8*)&Vb[(size_t)nt * 16 * N_ + jt * 32];
    mj[0] = Mb[jt * 32];
    mj[1] = Mb[jt * 32 + 16];
  };

  auto comp = [&](const float (&u)[8], const bf16x8 (&kf)[2][2], const bf16x8 (&vf)[4],
                  const float (&mj)[2]) {
    f32x4 S0 = f32x4{0.f, 0.f, 0.f, 0.f}, S1 = f32x4{0.f, 0.f, 0.f, 0.f};
#pragma unroll
    for (int kt = 0; kt < 2; ++kt) {
      S0 = MFMA16(qf[kt], kf[0][kt], S0);
      S1 = MFMA16(qf[kt], kf[1][kt], S1);
    }
#pragma unroll
    for (int e = 0; e < 4; ++e) {
      float s0 = S0[e] * SCALE_ + u[e * 2];
      float s1 = S1[e] * SCALE_ + u[e * 2 + 1];
      float p0 = (mj[0] != 0.f) ? exp2f(s0 * LOG2E_) : 0.f;
      float p1 = (mj[1] != 0.f) ? exp2f(s1 * LOG2E_) : 0.f;
      lrun[e] += p0 + p1;
      Plds[w][(lg * 4 + e) * 36 + lm] = p0;
      Plds[w][(lg * 4 + e) * 36 + lm + 16] = p1;
    }
    // P D->A relayout via per-wave LDS (within-wave lgkmcnt ordering)
    float4 pa0 = *(const float4*)&Plds[w][lm * 36 + lg * 8];
    float4 pa1 = *(const float4*)&Plds[w][lm * 36 + lg * 8 + 4];
    u32x4 pk;
    pk[0] = cvt_pk_bf16(pa0.x, pa0.y);
    pk[1] = cvt_pk_bf16(pa0.z, pa0.w);
    pk[2] = cvt_pk_bf16(pa1.x, pa1.y);
    pk[3] = cvt_pk_bf16(pa1.z, pa1.w);
    bf16x8 paf = __builtin_bit_cast(bf16x8, pk);
#pragma unroll
    for (int nt = 0; nt < 4; ++nt) acc[nt] = MFMA16(paf, vf[nt], acc[nt]);
  };

  pref(0, uA, kA, vA, mAv);
  for (int jt = 0; jt < 32; jt += 2) {
    pref(jt + 1, uB, kB, vB, mBv);
    comp(uA, kA, vA, mAv);
    if (jt + 2 < 32) pref(jt + 2, uA, kA, vA, mAv);
    comp(uB, kB, vB, mBv);
  }

  // epilogue: o = mask_i * (q + acc / sum)
#pragma unroll
  for (int e = 0; e < 4; ++e) {
    float lv = lrun[e];
    lv += __shfl_xor(lv, 1);
    lv += __shfl_xor(lv, 2);
    lv += __shfl_xor(lv, 4);
    lv += __shfl_xor(lv, 8);
    int gi = i0 + lg * 4 + e;
    float mi = mask[b * N_ + gi];
    float rD = 1.f / (lv + 1e-16f);
#pragma unroll
    for (int nt = 0; nt < 4; ++nt) {
      size_t off = ((size_t)b * N_ + gi) * D_ + h * DH_ + lm + nt * 16;
      float qv = bf2f(qb[off]);
      O32[off] = mi * (qv + acc[nt][e] * rD);
    }
  }
}

// ---------------------------------------------------------------------------
extern "C" void kernel_launch(void* const* d_in, const int* in_sizes, int n_in,
                              void* d_out, int out_size, void* d_ws, size_t ws_size,
                              hipStream_t stream) {
  const float* Q    = (const float*)d_in[0];
  const float* K    = (const float*)d_in[1];
  const float* U    = (const float*)d_in[2];
  const float* mask = (const float*)d_in[3];
  const float* Wq   = (const float*)d_in[4];
  const float* bq   = (const float*)d_in[5];
  const float* Wk   = (const float*)d_in[6];
  const float* bk   = (const float*)d_in[7];
  const float* Wv   = (const float*)d_in[8];
  const float* bv   = (const float*)d_in[9];
  const float* Wo   = (const float*)d_in[10];
  const float* bo   = (const float*)d_in[11];
  float* out = (float*)d_out;

  char* ws = (char*)d_ws;
  unsigned short* WT   = (unsigned short*)ws;                    // 2 MB (4 mats)
  unsigned short* qb   = (unsigned short*)(ws + (2llu << 20));   // 8 MB
  unsigned short* kb   = (unsigned short*)(ws + (10llu << 20));  // 8 MB
  unsigned short* vtmp = (unsigned short*)(ws + (18llu << 20));  // 8 MB
  unsigned short* vTb  = (unsigned short*)(ws + (26llu << 20));  // 8 MB
  float* O32           = (float*)(ws + (34llu << 20));           // 16 MB -> 50 MB

  prep_w<<<4096, 256, 0, stream>>>(Wq, Wk, Wv, Wo, WT);
  gemm_proj3<<<dim3(256, 3), 256, 0, stream>>>(Q, K, WT, bq, bk, bv, mask, qb, kb, vtmp);
  vtrans_kernel<<<dim3(8, 16, 8), 256, 0, stream>>>(vtmp, vTb);
  attn_kernel<<<512, 512, 0, stream>>>(qb, kb, vTb, U, mask, O32);
  gemm_final<<<256, 256, 0, stream>>>(O32, WT + 3 * 262144, bo, mask, O32, out);
}

// Round 4
// 240.442 us; speedup vs baseline: 1.3529x; 1.3529x over previous
//
#include <hip/hip_runtime.h>

#define B_   8
#define N_   1024
#define D_   512
#define H_   8
#define DH_  64
#define SCALE_ 0.044194173824159216f   // 1/sqrt(512)
#define LOG2E_ 1.4426950408889634f

typedef __attribute__((ext_vector_type(8))) short bf16x8;
typedef __attribute__((ext_vector_type(4))) float f32x4;
typedef __attribute__((ext_vector_type(8))) unsigned short us8;
typedef __attribute__((ext_vector_type(4))) unsigned int u32x4;

__device__ __forceinline__ unsigned short f2bf(float f) {
  unsigned u = __builtin_bit_cast(unsigned, f);
  u += 0x7fffu + ((u >> 16) & 1u);           // RNE
  return (unsigned short)(u >> 16);
}
__device__ __forceinline__ float bf2f(unsigned short h) {
  unsigned u = ((unsigned)h) << 16;
  return __builtin_bit_cast(float, u);
}
__device__ __forceinline__ void gl_lds16(const void* g, void* l) {
  __builtin_amdgcn_global_load_lds(
      (const __attribute__((address_space(1))) unsigned int*)g,
      (__attribute__((address_space(3))) unsigned int*)l, 16, 0, 0);
}
__device__ __forceinline__ unsigned cvt_pk_bf16(float lo, float hi) {
  unsigned r;
  asm("v_cvt_pk_bf16_f32 %0, %1, %2" : "=v"(r) : "v"(lo), "v"(hi));
  return r;
}
#define MFMA16(a, b, c) __builtin_amdgcn_mfma_f32_16x16x32_bf16((a), (b), (c), 0, 0, 0)

// ---------------------------------------------------------------------------
// prep: WT_swz[mat][n][kmap] = bf16(W[k][n]); kmap XOR-swizzled so that a
// LINEAR global_load_lds copy + XOR on the ds_read side is bank-conflict-free.
// ---------------------------------------------------------------------------
__global__ void prep_w(const float* __restrict__ Wq, const float* __restrict__ Wk,
                       const float* __restrict__ Wv, const float* __restrict__ Wo,
                       unsigned short* __restrict__ WT) {
  int idx = blockIdx.x * 256 + threadIdx.x;          // 4 * 512 * 512 total
  int mat = idx >> 18;
  int rem = idx & 0x3FFFF;
  int k = rem >> 9, n = rem & 511;
  const float* W = (mat == 0) ? Wq : (mat == 1) ? Wk : (mat == 2) ? Wv : Wo;
  float v = W[(size_t)k * 512 + n];
  int kmap = (k & ~63) | ((k & 63) ^ ((n & 7) << 3));
  WT[(size_t)mat * 262144 + (size_t)n * 512 + kmap] = f2bf(v);
}

// ---------------------------------------------------------------------------
// GEMM core body (128x128 tile, BK=64, 4 waves 2x2, wave = 64x64 out)
// ---------------------------------------------------------------------------
#define GEMM_BODY(A, W, bias, EPILOGUE)                                          \
  __shared__ unsigned short Alds[2][128][72];                                    \
  __shared__ unsigned short Blds[2][128 * 64];                                   \
  const int t = threadIdx.x, w = t >> 6, l = t & 63;                             \
  const int wr = w >> 1, wc = w & 1;                                             \
  const int lm = l & 15, lg = l >> 4;                                            \
  const int bm = blockIdx.x >> 2, bn = blockIdx.x & 3;                           \
  f32x4 acc[4][4];                                                               \
  _Pragma("unroll") for (int mt = 0; mt < 4; ++mt)                               \
  _Pragma("unroll") for (int nt = 0; nt < 4; ++nt)                               \
      acc[mt][nt] = f32x4{0.f, 0.f, 0.f, 0.f};                                   \
  float4 areg[8];                                                                \
  auto loadA = [&](int kt) {                                                     \
    _Pragma("unroll") for (int p = 0; p < 8; ++p) {                              \
      int row = (t >> 4) + p * 16, col = (t & 15) * 4;                           \
      areg[p] = *(const float4*)&A[((size_t)(bm * 128 + row)) * 512 + kt * 64 + col]; \
    }                                                                            \
  };                                                                             \
  auto issueB = [&](int kt, int sb) {                                            \
    _Pragma("unroll") for (int p = 0; p < 4; ++p) {                              \
      int chunk = w * 4 + p;                                                     \
      int row = chunk * 8 + (l >> 3), gc = kt * 64 + (l & 7) * 8;                \
      gl_lds16(&W[((size_t)(bn * 128 + row)) * 512 + gc],                        \
               &Blds[sb][chunk * 512 + l * 8]);                                  \
    }                                                                            \
  };                                                                             \
  auto writeA = [&](int sb) {                                                    \
    _Pragma("unroll") for (int p = 0; p < 8; ++p) {                              \
      int row = (t >> 4) + p * 16, col = (t & 15) * 4;                           \
      float4 v = areg[p];                                                        \
      uint2 d;                                                                   \
      d.x = (unsigned)f2bf(v.x) | ((unsigned)f2bf(v.y) << 16);                   \
      d.y = (unsigned)f2bf(v.z) | ((unsigned)f2bf(v.w) << 16);                   \
      *(uint2*)&Alds[sb][row][col] = d;                                          \
    }                                                                            \
  };                                                                             \
  loadA(0); issueB(0, 0); writeA(0);                                             \
  __syncthreads();                                                               \
  int buf = 0;                                                                   \
  for (int kt = 0; kt < 8; ++kt) {                                               \
    if (kt + 1 < 8) { loadA(kt + 1); issueB(kt + 1, buf ^ 1); }                  \
    _Pragma("unroll") for (int kk = 0; kk < 2; ++kk) {                           \
      bf16x8 af[4], bfv[4];                                                      \
      _Pragma("unroll") for (int mt = 0; mt < 4; ++mt)                           \
        af[mt] = *(const bf16x8*)&Alds[buf][wr * 64 + mt * 16 + lm][kk * 32 + lg * 8]; \
      _Pragma("unroll") for (int nt = 0; nt < 4; ++nt) {                         \
        int rr = wc * 64 + nt * 16 + lm;                                         \
        int c = (kk * 32 + lg * 8) ^ ((rr & 7) << 3);                            \
        bfv[nt] = *(const bf16x8*)&Blds[buf][rr * 64 + c];                       \
      }                                                                          \
      _Pragma("unroll") for (int mt = 0; mt < 4; ++mt)                           \
      _Pragma("unroll") for (int nt = 0; nt < 4; ++nt)                           \
          acc[mt][nt] = MFMA16(af[mt], bfv[nt], acc[mt][nt]);                    \
    }                                                                            \
    if (kt + 1 < 8) writeA(buf ^ 1);                                             \
    __syncthreads();                                                             \
    buf ^= 1;                                                                    \
  }                                                                              \
  _Pragma("unroll") for (int mt = 0; mt < 4; ++mt)                               \
  _Pragma("unroll") for (int nt = 0; nt < 4; ++nt) {                             \
    int gn = bn * 128 + wc * 64 + nt * 16 + lm;                                  \
    float bv_ = bias[gn];                                                        \
    _Pragma("unroll") for (int e = 0; e < 4; ++e) {                              \
      int gm = bm * 128 + wr * 64 + mt * 16 + lg * 4 + e;                        \
      float v = acc[mt][nt][e] + bv_;                                            \
      size_t off = (size_t)gm * 512 + gn;                                        \
      EPILOGUE                                                                   \
    }                                                                            \
  }

// fused 3 projection GEMMs: blockIdx.y = {0:Q->qb, 1:K->kb, 2:K->vtmp}
__global__ __launch_bounds__(256, 2) void gemm_proj3(
    const float* __restrict__ Q, const float* __restrict__ K,
    const unsigned short* __restrict__ WT,
    const float* __restrict__ bq, const float* __restrict__ bk,
    const float* __restrict__ bv, const float* __restrict__ mask,
    unsigned short* __restrict__ qb, unsigned short* __restrict__ kb,
    unsigned short* __restrict__ vtmp) {
  const int mat = blockIdx.y;
  const float* A = (mat == 0) ? Q : K;
  const unsigned short* W = WT + (size_t)mat * 262144;
  const float* bias = (mat == 0) ? bq : (mat == 1) ? bk : bv;
  unsigned short* outp = (mat == 0) ? qb : (mat == 1) ? kb : vtmp;
  GEMM_BODY(A, W, bias, { outp[off] = f2bf(v * mask[gm]); })
}

// final GEMM: out_f32 = resid + relu(acc + bias) * mask
__global__ __launch_bounds__(256, 2) void gemm_final(
    const float* __restrict__ A, const unsigned short* __restrict__ W,
    const float* __restrict__ bias, const float* __restrict__ mask,
    const float* __restrict__ resid, float* __restrict__ outp) {
  GEMM_BODY(A, W, bias, { outp[off] = resid[off] + fmaxf(v, 0.f) * mask[gm]; })
}

// ---------------------------------------------------------------------------
// v transpose: vtmp[b][n][d] (bf16) -> vT[b][d][n] (bf16)
// ---------------------------------------------------------------------------
__global__ void vtrans_kernel(const unsigned short* __restrict__ vtmp,
                              unsigned short* __restrict__ vT) {
  __shared__ unsigned short T[64][72];
  int b = blockIdx.x, ntile = blockIdx.y, dtile = blockIdx.z;
  int n0 = ntile * 64, d0 = dtile * 64;
  int t = threadIdx.x;
#pragma unroll
  for (int p = 0; p < 2; ++p) {
    int r = (t >> 3) + p * 32;
    int c = (t & 7) * 8;
    *(us8*)&T[r][c] = *(const us8*)&vtmp[((size_t)(b * N_ + n0 + r)) * D_ + d0 + c];
  }
  __syncthreads();
#pragma unroll
  for (int p = 0; p < 2; ++p) {
    int r = (t >> 3) + p * 32;   // d-local
    int c = (t & 7) * 8;         // n-local
    us8 v;
#pragma unroll
    for (int e = 0; e < 8; ++e) v[e] = T[c + e][r];
    *(us8*)&vT[((size_t)(b * D_ + d0 + r)) * N_ + n0 + c] = v;
  }
}

// ---------------------------------------------------------------------------
// attention: block = (h = bid&7 -> one h per XCD, i-tile of 16 rows).
// 8 waves = 8 batches. U reg-staged into swizzled LDS (2-way-free reads),
// rolling K prefetch (next iter), V/mask loaded at iter top (consumed late).
// LDS 50.4 KB -> 2 blocks/CU.
// ---------------------------------------------------------------------------
__global__ __launch_bounds__(512, 4) void attn_kernel(
    const unsigned short* __restrict__ qb, const unsigned short* __restrict__ kb,
    const unsigned short* __restrict__ vT, const float* __restrict__ U,
    const float* __restrict__ mask, float* __restrict__ O32) {
  __shared__ float Ulds[2][4096];      // [i16][j32][b8] swizzled, 16 KB each
  __shared__ float Plds[8][16 * 36];   // 18.4 KB
  const int t = threadIdx.x, w = t >> 6, l = t & 63;
  const int bid = (int)blockIdx.x;
  const int h = bid & 7;               // XCD-aligned: head h lives on XCD h
  const int i0 = (bid >> 3) * 16;
  const int b = w;
  const int lm = l & 15, lg = l >> 4;

  // ---- U staging (write side): thread t owns U[i=t>>5][j=t&31][b=0..7]
  const int sti = t >> 5, stj = t & 31;
  const float* Ug = U + (((size_t)h * N_ + i0 + sti) * N_ + stj) * B_;
  // physical: dword = i*256 + ((j ^ (i>>2))&31)*8 + ((b>>2)^((j>>2)&1))*4 + ((b&3)^(j&3))
  const int pbase = sti * 256 + ((stj ^ (sti >> 2)) & 31) * 8;
  const int bh0 = (stj >> 2) & 1;
  const int rot = stj & 3;

  float4 ua, ubv;
  auto stageLoad = [&](int jt) {
    const float* g = Ug + (size_t)jt * 256;
    ua  = *(const float4*)(g);
    ubv = *(const float4*)(g + 4);
  };
  auto rot4 = [&](float4 v) {
    if (rot & 1) v = float4{v.y, v.x, v.w, v.z};
    if (rot & 2) v = float4{v.z, v.w, v.x, v.y};
    return v;
  };
  auto stageWrite = [&](int sb) {
    *(float4*)&Ulds[sb][pbase + (0 ^ bh0) * 4] = rot4(ua);
    *(float4*)&Ulds[sb][pbase + (1 ^ bh0) * 4] = rot4(ubv);
  };

  // ---- U read base for lane (reads its own b=w):
  // dword = lg*1024 + e*256 + hb*128 + (lm^lg)*8 + ((w>>2)^((lm>>2)&1))*4 + ((w&3)^(lm&3))
  const int ubase = ((lm ^ lg) * 8) + (((w >> 2) ^ ((lm >> 2) & 1)) * 4) + ((w & 3) ^ (lm & 3)) + lg * 1024;

  // per-lane K/V/mask bases
  const unsigned short* Kb = kb + (size_t)b * N_ * D_ + h * DH_ + lg * 8;
  const unsigned short* Vb = vT + ((size_t)b * D_ + h * DH_ + lm) * N_ + lg * 8;
  const float* Mb = mask + b * N_ + lm;

  // Q fragments (A-layout), resident for the whole block
  bf16x8 qf[2];
#pragma unroll
  for (int kt = 0; kt < 2; ++kt)
    qf[kt] = *(const bf16x8*)&qb[((size_t)b * N_ + i0 + lm) * D_ + h * DH_ + kt * 32 + lg * 8];

  f32x4 acc[4];
#pragma unroll
  for (int nt = 0; nt < 4; ++nt) acc[nt] = f32x4{0.f, 0.f, 0.f, 0.f};
  float lrun[4] = {0.f, 0.f, 0.f, 0.f};

  bf16x8 kf[2][2], vf[4];
  auto loadK = [&](int jt) {
#pragma unroll
    for (int j2 = 0; j2 < 2; ++j2)
#pragma unroll
      for (int kt = 0; kt < 2; ++kt)
        kf[j2][kt] = *(const bf16x8*)&Kb[(size_t)(jt * 32 + j2 * 16 + lm) * D_ + kt * 32];
  };

  // prologue
  stageLoad(0);
  stageWrite(0);
  loadK(0);
  __syncthreads();

  for (int jt = 0; jt < 32; ++jt) {
    const int buf = jt & 1;
    if (jt + 1 < 32) stageLoad(jt + 1);
    // V + mask for THIS tile (consumed late -> latency hidden under QK+softmax)
#pragma unroll
    for (int nt = 0; nt < 4; ++nt)
      vf[nt] = *(const bf16x8*)&Vb[(size_t)nt * 16 * N_ + jt * 32];
    float mj0 = Mb[jt * 32];
    float mj1 = Mb[jt * 32 + 16];

    // S = q @ k^T (kf loaded last iteration)
    f32x4 S0 = f32x4{0.f, 0.f, 0.f, 0.f}, S1 = f32x4{0.f, 0.f, 0.f, 0.f};
#pragma unroll
    for (int kt = 0; kt < 2; ++kt) {
      S0 = MFMA16(qf[kt], kf[0][kt], S0);
      S1 = MFMA16(qf[kt], kf[1][kt], S1);
    }
    // rolling K prefetch for next tile (regs free after QK)
    if (jt + 1 < 32) loadK(jt + 1);

    // softmax numerators (no max subtraction: |s| bounded ~1)
#pragma unroll
    for (int e = 0; e < 4; ++e) {
      float u0 = Ulds[buf][e * 256 + ubase];
      float u1 = Ulds[buf][e * 256 + 128 + ubase];
      float s0 = S0[e] * SCALE_ + u0;
      float s1 = S1[e] * SCALE_ + u1;
      float p0 = (mj0 != 0.f) ? exp2f(s0 * LOG2E_) : 0.f;
      float p1 = (mj1 != 0.f) ? exp2f(s1 * LOG2E_) : 0.f;
      lrun[e] += p0 + p1;
      Plds[w][(lg * 4 + e) * 36 + lm] = p0;
      Plds[w][(lg * 4 + e) * 36 + lm + 16] = p1;
    }
    // P D->A relayout via per-wave LDS (within-wave lgkmcnt ordering)
    float4 pa0 = *(const float4*)&Plds[w][lm * 36 + lg * 8];
    float4 pa1 = *(const float4*)&Plds[w][lm * 36 + lg * 8 + 4];
    u32x4 pk;
    pk[0] = cvt_pk_bf16(pa0.x, pa0.y);
    pk[1] = cvt_pk_bf16(pa0.z, pa0.w);
    pk[2] = cvt_pk_bf16(pa1.x, pa1.y);
    pk[3] = cvt_pk_bf16(pa1.z, pa1.w);
    bf16x8 paf = __builtin_bit_cast(bf16x8, pk);
#pragma unroll
    for (int nt = 0; nt < 4; ++nt) acc[nt] = MFMA16(paf, vf[nt], acc[nt]);

    if (jt + 1 < 32) stageWrite(buf ^ 1);
    __syncthreads();
  }

  // epilogue: o = mask_i * (q + acc / sum)
#pragma unroll
  for (int e = 0; e < 4; ++e) {
    float lv = lrun[e];
    lv += __shfl_xor(lv, 1);
    lv += __shfl_xor(lv, 2);
    lv += __shfl_xor(lv, 4);
    lv += __shfl_xor(lv, 8);
    int gi = i0 + lg * 4 + e;
    float mi = mask[b * N_ + gi];
    float rD = 1.f / (lv + 1e-16f);
#pragma unroll
    for (int nt = 0; nt < 4; ++nt) {
      size_t off = ((size_t)b * N_ + gi) * D_ + h * DH_ + lm + nt * 16;
      float qv = bf2f(qb[off]);
      O32[off] = mi * (qv + acc[nt][e] * rD);
    }
  }
}

// ---------------------------------------------------------------------------
extern "C" void kernel_launch(void* const* d_in, const int* in_sizes, int n_in,
                              void* d_out, int out_size, void* d_ws, size_t ws_size,
                              hipStream_t stream) {
  const float* Q    = (const float*)d_in[0];
  const float* K    = (const float*)d_in[1];
  const float* U    = (const float*)d_in[2];
  const float* mask = (const float*)d_in[3];
  const float* Wq   = (const float*)d_in[4];
  const float* bq   = (const float*)d_in[5];
  const float* Wk   = (const float*)d_in[6];
  const float* bk   = (const float*)d_in[7];
  const float* Wv   = (const float*)d_in[8];
  const float* bv   = (const float*)d_in[9];
  const float* Wo   = (const float*)d_in[10];
  const float* bo   = (const float*)d_in[11];
  float* out = (float*)d_out;

  char* ws = (char*)d_ws;
  unsigned short* WT   = (unsigned short*)ws;                    // 2 MB (4 mats)
  unsigned short* qb   = (unsigned short*)(ws + (2llu << 20));   // 8 MB
  unsigned short* kb   = (unsigned short*)(ws + (10llu << 20));  // 8 MB
  unsigned short* vtmp = (unsigned short*)(ws + (18llu << 20));  // 8 MB
  unsigned short* vTb  = (unsigned short*)(ws + (26llu << 20));  // 8 MB
  float* O32           = (float*)(ws + (34llu << 20));           // 16 MB -> 50 MB

  prep_w<<<4096, 256, 0, stream>>>(Wq, Wk, Wv, Wo, WT);
  gemm_proj3<<<dim3(256, 3), 256, 0, stream>>>(Q, K, WT, bq, bk, bv, mask, qb, kb, vtmp);
  vtrans_kernel<<<dim3(8, 16, 8), 256, 0, stream>>>(vtmp, vTb);
  attn_kernel<<<512, 512, 0, stream>>>(qb, kb, vTb, U, mask, O32);
  gemm_final<<<256, 256, 0, stream>>>(O32, WT + 3 * 262144, bo, mask, O32, out);
}

// Round 5
// 231.752 us; speedup vs baseline: 1.4036x; 1.0375x over previous
//
#include <hip/hip_runtime.h>

#define B_   8
#define N_   1024
#define D_   512
#define H_   8
#define DH_  64
#define SCALE_ 0.044194173824159216f   // 1/sqrt(512)
#define LOG2E_ 1.4426950408889634f

typedef __attribute__((ext_vector_type(8))) short bf16x8;
typedef __attribute__((ext_vector_type(4))) float f32x4;
typedef __attribute__((ext_vector_type(8))) unsigned short us8;
typedef __attribute__((ext_vector_type(4))) unsigned int u32x4;

__device__ __forceinline__ unsigned short f2bf(float f) {
  unsigned u = __builtin_bit_cast(unsigned, f);
  u += 0x7fffu + ((u >> 16) & 1u);           // RNE
  return (unsigned short)(u >> 16);
}
__device__ __forceinline__ float bf2f(unsigned short h) {
  unsigned u = ((unsigned)h) << 16;
  return __builtin_bit_cast(float, u);
}
__device__ __forceinline__ void gl_lds16(const void* g, void* l) {
  __builtin_amdgcn_global_load_lds(
      (const __attribute__((address_space(1))) unsigned int*)g,
      (__attribute__((address_space(3))) unsigned int*)l, 16, 0, 0);
}
__device__ __forceinline__ unsigned cvt_pk_bf16(float lo, float hi) {
  unsigned r;
  asm("v_cvt_pk_bf16_f32 %0, %1, %2" : "=v"(r) : "v"(lo), "v"(hi));
  return r;
}
#define MFMA16(a, b, c) __builtin_amdgcn_mfma_f32_16x16x32_bf16((a), (b), (c), 0, 0, 0)
#define SCHED_PIN() __builtin_amdgcn_sched_barrier(0)

// ---------------------------------------------------------------------------
// prep: WT_swz[mat][n][kmap] = bf16(W[k][n]); kmap XOR-swizzled so that a
// LINEAR global_load_lds copy + XOR on the ds_read side is bank-conflict-free.
// ---------------------------------------------------------------------------
__global__ void prep_w(const float* __restrict__ Wq, const float* __restrict__ Wk,
                       const float* __restrict__ Wv, const float* __restrict__ Wo,
                       unsigned short* __restrict__ WT) {
  int idx = blockIdx.x * 256 + threadIdx.x;          // 4 * 512 * 512 total
  int mat = idx >> 18;
  int rem = idx & 0x3FFFF;
  int k = rem >> 9, n = rem & 511;
  const float* W = (mat == 0) ? Wq : (mat == 1) ? Wk : (mat == 2) ? Wv : Wo;
  float v = W[(size_t)k * 512 + n];
  int kmap = (k & ~63) | ((k & 63) ^ ((n & 7) << 3));
  WT[(size_t)mat * 262144 + (size_t)n * 512 + kmap] = f2bf(v);
}

// ---------------------------------------------------------------------------
// GEMM core body (128x128 tile, BK=64, 4 waves 2x2, wave = 64x64 out)
// ---------------------------------------------------------------------------
#define GEMM_BODY(A, W, bias, EPILOGUE)                                          \
  __shared__ unsigned short Alds[2][128][72];                                    \
  __shared__ unsigned short Blds[2][128 * 64];                                   \
  const int t = threadIdx.x, w = t >> 6, l = t & 63;                             \
  const int wr = w >> 1, wc = w & 1;                                             \
  const int lm = l & 15, lg = l >> 4;                                            \
  const int bm = blockIdx.x >> 2, bn = blockIdx.x & 3;                           \
  f32x4 acc[4][4];                                                               \
  _Pragma("unroll") for (int mt = 0; mt < 4; ++mt)                               \
  _Pragma("unroll") for (int nt = 0; nt < 4; ++nt)                               \
      acc[mt][nt] = f32x4{0.f, 0.f, 0.f, 0.f};                                   \
  float4 areg[8];                                                                \
  auto loadA = [&](int kt) {                                                     \
    _Pragma("unroll") for (int p = 0; p < 8; ++p) {                              \
      int row = (t >> 4) + p * 16, col = (t & 15) * 4;                           \
      areg[p] = *(const float4*)&A[((size_t)(bm * 128 + row)) * 512 + kt * 64 + col]; \
    }                                                                            \
  };                                                                             \
  auto issueB = [&](int kt, int sb) {                                            \
    _Pragma("unroll") for (int p = 0; p < 4; ++p) {                              \
      int chunk = w * 4 + p;                                                     \
      int row = chunk * 8 + (l >> 3), gc = kt * 64 + (l & 7) * 8;                \
      gl_lds16(&W[((size_t)(bn * 128 + row)) * 512 + gc],                        \
               &Blds[sb][chunk * 512 + l * 8]);                                  \
    }                                                                            \
  };                                                                             \
  auto writeA = [&](int sb) {                                                    \
    _Pragma("unroll") for (int p = 0; p < 8; ++p) {                              \
      int row = (t >> 4) + p * 16, col = (t & 15) * 4;                           \
      float4 v = areg[p];                                                        \
      uint2 d;                                                                   \
      d.x = (unsigned)f2bf(v.x) | ((unsigned)f2bf(v.y) << 16);                   \
      d.y = (unsigned)f2bf(v.z) | ((unsigned)f2bf(v.w) << 16);                   \
      *(uint2*)&Alds[sb][row][col] = d;                                          \
    }                                                                            \
  };                                                                             \
  loadA(0); issueB(0, 0); writeA(0);                                             \
  __syncthreads();                                                               \
  int buf = 0;                                                                   \
  for (int kt = 0; kt < 8; ++kt) {                                               \
    if (kt + 1 < 8) { loadA(kt + 1); issueB(kt + 1, buf ^ 1); }                  \
    _Pragma("unroll") for (int kk = 0; kk < 2; ++kk) {                           \
      bf16x8 af[4], bfv[4];                                                      \
      _Pragma("unroll") for (int mt = 0; mt < 4; ++mt)                           \
        af[mt] = *(const bf16x8*)&Alds[buf][wr * 64 + mt * 16 + lm][kk * 32 + lg * 8]; \
      _Pragma("unroll") for (int nt = 0; nt < 4; ++nt) {                         \
        int rr = wc * 64 + nt * 16 + lm;                                         \
        int c = (kk * 32 + lg * 8) ^ ((rr & 7) << 3);                            \
        bfv[nt] = *(const bf16x8*)&Blds[buf][rr * 64 + c];                       \
      }                                                                          \
      _Pragma("unroll") for (int mt = 0; mt < 4; ++mt)                           \
      _Pragma("unroll") for (int nt = 0; nt < 4; ++nt)                           \
          acc[mt][nt] = MFMA16(af[mt], bfv[nt], acc[mt][nt]);                    \
    }                                                                            \
    if (kt + 1 < 8) writeA(buf ^ 1);                                             \
    __syncthreads();                                                             \
    buf ^= 1;                                                                    \
  }                                                                              \
  _Pragma("unroll") for (int mt = 0; mt < 4; ++mt)                               \
  _Pragma("unroll") for (int nt = 0; nt < 4; ++nt) {                             \
    int gn = bn * 128 + wc * 64 + nt * 16 + lm;                                  \
    float bv_ = bias[gn];                                                        \
    _Pragma("unroll") for (int e = 0; e < 4; ++e) {                              \
      int gm = bm * 128 + wr * 64 + mt * 16 + lg * 4 + e;                        \
      float v = acc[mt][nt][e] + bv_;                                            \
      size_t off = (size_t)gm * 512 + gn;                                        \
      EPILOGUE                                                                   \
    }                                                                            \
  }

// fused 3 projection GEMMs: blockIdx.y = {0:Q->qb, 1:K->kb, 2:K->vtmp}
__global__ __launch_bounds__(256, 2) void gemm_proj3(
    const float* __restrict__ Q, const float* __restrict__ K,
    const unsigned short* __restrict__ WT,
    const float* __restrict__ bq, const float* __restrict__ bk,
    const float* __restrict__ bv, const float* __restrict__ mask,
    unsigned short* __restrict__ qb, unsigned short* __restrict__ kb,
    unsigned short* __restrict__ vtmp) {
  const int mat = blockIdx.y;
  const float* A = (mat == 0) ? Q : K;
  const unsigned short* W = WT + (size_t)mat * 262144;
  const float* bias = (mat == 0) ? bq : (mat == 1) ? bk : bv;
  unsigned short* outp = (mat == 0) ? qb : (mat == 1) ? kb : vtmp;
  GEMM_BODY(A, W, bias, { outp[off] = f2bf(v * mask[gm]); })
}

// final GEMM: out_f32 = resid + relu(acc + bias) * mask
__global__ __launch_bounds__(256, 2) void gemm_final(
    const float* __restrict__ A, const unsigned short* __restrict__ W,
    const float* __restrict__ bias, const float* __restrict__ mask,
    const float* __restrict__ resid, float* __restrict__ outp) {
  GEMM_BODY(A, W, bias, { outp[off] = resid[off] + fmaxf(v, 0.f) * mask[gm]; })
}

// ---------------------------------------------------------------------------
// v transpose: vtmp[b][n][d] (bf16) -> vT[b][d][n] (bf16)
// ---------------------------------------------------------------------------
__global__ void vtrans_kernel(const unsigned short* __restrict__ vtmp,
                              unsigned short* __restrict__ vT) {
  __shared__ unsigned short T[64][72];
  int b = blockIdx.x, ntile = blockIdx.y, dtile = blockIdx.z;
  int n0 = ntile * 64, d0 = dtile * 64;
  int t = threadIdx.x;
#pragma unroll
  for (int p = 0; p < 2; ++p) {
    int r = (t >> 3) + p * 32;
    int c = (t & 7) * 8;
    *(us8*)&T[r][c] = *(const us8*)&vtmp[((size_t)(b * N_ + n0 + r)) * D_ + d0 + c];
  }
  __syncthreads();
#pragma unroll
  for (int p = 0; p < 2; ++p) {
    int r = (t >> 3) + p * 32;   // d-local
    int c = (t & 7) * 8;         // n-local
    us8 v;
#pragma unroll
    for (int e = 0; e < 8; ++e) v[e] = T[c + e][r];
    *(us8*)&vT[((size_t)(b * D_ + d0 + r)) * N_ + n0 + c] = v;
  }
}

// ---------------------------------------------------------------------------
// attention: block = (h = bid&7 -> one h per XCD, i-tile of 16 rows).
// 8 waves = 8 batches. U reg-staged into swizzled LDS (2-way-free reads),
// rolling K prefetch, V loaded early. sched_barrier(0) pins the prefetch
// issue points so the scheduler cannot sink loads to their uses (r4 failure:
// VGPR=56 proved loads were sunk, exposing full latency each iteration).
// ---------------------------------------------------------------------------
__global__ __launch_bounds__(512, 2) void attn_kernel(
    const unsigned short* __restrict__ qb, const unsigned short* __restrict__ kb,
    const unsigned short* __restrict__ vT, const float* __restrict__ U,
    const float* __restrict__ mask, float* __restrict__ O32) {
  __shared__ float Ulds[2][4096];      // [i16][j32][b8] swizzled, 16 KB each
  __shared__ float Plds[8][16 * 36];   // 18.4 KB
  const int t = threadIdx.x, w = t >> 6, l = t & 63;
  const int bid = (int)blockIdx.x;
  const int h = bid & 7;               // XCD-aligned: head h lives on XCD h
  const int i0 = (bid >> 3) * 16;
  const int b = w;
  const int lm = l & 15, lg = l >> 4;

  // ---- U staging (write side): thread t owns U[i=t>>5][j=t&31][b=0..7]
  const int sti = t >> 5, stj = t & 31;
  const float* Ug = U + (((size_t)h * N_ + i0 + sti) * N_ + stj) * B_;
  // physical: dword = i*256 + ((j ^ (i>>2))&31)*8 + ((b>>2)^((j>>2)&1))*4 + ((b&3)^(j&3))
  const int pbase = sti * 256 + ((stj ^ (sti >> 2)) & 31) * 8;
  const int bh0 = (stj >> 2) & 1;
  const int rot = stj & 3;

  float4 ua, ubv;
  auto stageLoad = [&](int jt) {
    const float* g = Ug + (size_t)jt * 256;
    ua  = *(const float4*)(g);
    ubv = *(const float4*)(g + 4);
  };
  auto rot4 = [&](float4 v) {
    if (rot & 1) v = float4{v.y, v.x, v.w, v.z};
    if (rot & 2) v = float4{v.z, v.w, v.x, v.y};
    return v;
  };
  auto stageWrite = [&](int sb) {
    *(float4*)&Ulds[sb][pbase + (0 ^ bh0) * 4] = rot4(ua);
    *(float4*)&Ulds[sb][pbase + (1 ^ bh0) * 4] = rot4(ubv);
  };

  // ---- U read base for lane (reads its own b=w):
  const int ubase = ((lm ^ lg) * 8) + (((w >> 2) ^ ((lm >> 2) & 1)) * 4) + ((w & 3) ^ (lm & 3)) + lg * 1024;

  // per-lane K/V/mask bases
  const unsigned short* Kb = kb + (size_t)b * N_ * D_ + h * DH_ + lg * 8;
  const unsigned short* Vb = vT + ((size_t)b * D_ + h * DH_ + lm) * N_ + lg * 8;
  const float* Mb = mask + b * N_ + lm;

  // Q fragments (A-layout), resident for the whole block
  bf16x8 qf[2];
#pragma unroll
  for (int kt = 0; kt < 2; ++kt)
    qf[kt] = *(const bf16x8*)&qb[((size_t)b * N_ + i0 + lm) * D_ + h * DH_ + kt * 32 + lg * 8];

  f32x4 acc[4];
#pragma unroll
  for (int nt = 0; nt < 4; ++nt) acc[nt] = f32x4{0.f, 0.f, 0.f, 0.f};
  float lrun[4] = {0.f, 0.f, 0.f, 0.f};

  bf16x8 kf[2][2], vf[4];
  auto loadK = [&](int jt) {
#pragma unroll
    for (int j2 = 0; j2 < 2; ++j2)
#pragma unroll
      for (int kt = 0; kt < 2; ++kt)
        kf[j2][kt] = *(const bf16x8*)&Kb[(size_t)(jt * 32 + j2 * 16 + lm) * D_ + kt * 32];
  };

  // prologue
  stageLoad(0);
  stageWrite(0);
  loadK(0);
  __syncthreads();

  for (int jt = 0; jt < 32; ++jt) {
    const int buf = jt & 1;
    // ---- issue group (pinned): U(jt+1), V(jt), mask(jt) ----
    if (jt + 1 < 32) stageLoad(jt + 1);
#pragma unroll
    for (int nt = 0; nt < 4; ++nt)
      vf[nt] = *(const bf16x8*)&Vb[(size_t)nt * 16 * N_ + jt * 32];
    float mj0 = Mb[jt * 32];
    float mj1 = Mb[jt * 32 + 16];
    SCHED_PIN();   // loads above must issue HERE, not at their uses

    // S = q @ k^T (kf loaded last iteration)
    f32x4 S0 = f32x4{0.f, 0.f, 0.f, 0.f}, S1 = f32x4{0.f, 0.f, 0.f, 0.f};
#pragma unroll
    for (int kt = 0; kt < 2; ++kt) {
      S0 = MFMA16(qf[kt], kf[0][kt], S0);
      S1 = MFMA16(qf[kt], kf[1][kt], S1);
    }
    // rolling K prefetch for next tile (regs free after QK)
    if (jt + 1 < 32) loadK(jt + 1);
    SCHED_PIN();   // K prefetch issues before softmax, stays live to next iter

    // softmax numerators (no max subtraction: |s| bounded ~1)
#pragma unroll
    for (int e = 0; e < 4; ++e) {
      float u0 = Ulds[buf][e * 256 + ubase];
      float u1 = Ulds[buf][e * 256 + 128 + ubase];
      float s0 = S0[e] * SCALE_ + u0;
      float s1 = S1[e] * SCALE_ + u1;
      float p0 = (mj0 != 0.f) ? exp2f(s0 * LOG2E_) : 0.f;
      float p1 = (mj1 != 0.f) ? exp2f(s1 * LOG2E_) : 0.f;
      lrun[e] += p0 + p1;
      Plds[w][(lg * 4 + e) * 36 + lm] = p0;
      Plds[w][(lg * 4 + e) * 36 + lm + 16] = p1;
    }
    // P D->A relayout via per-wave LDS (within-wave lgkmcnt ordering)
    float4 pa0 = *(const float4*)&Plds[w][lm * 36 + lg * 8];
    float4 pa1 = *(const float4*)&Plds[w][lm * 36 + lg * 8 + 4];
    u32x4 pk;
    pk[0] = cvt_pk_bf16(pa0.x, pa0.y);
    pk[1] = cvt_pk_bf16(pa0.z, pa0.w);
    pk[2] = cvt_pk_bf16(pa1.x, pa1.y);
    pk[3] = cvt_pk_bf16(pa1.z, pa1.w);
    bf16x8 paf = __builtin_bit_cast(bf16x8, pk);
#pragma unroll
    for (int nt = 0; nt < 4; ++nt) acc[nt] = MFMA16(paf, vf[nt], acc[nt]);

    if (jt + 1 < 32) stageWrite(buf ^ 1);   // ua/ubv issued a full iter ago
    __syncthreads();
  }

  // epilogue: o = mask_i * (q + acc / sum)
#pragma unroll
  for (int e = 0; e < 4; ++e) {
    float lv = lrun[e];
    lv += __shfl_xor(lv, 1);
    lv += __shfl_xor(lv, 2);
    lv += __shfl_xor(lv, 4);
    lv += __shfl_xor(lv, 8);
    int gi = i0 + lg * 4 + e;
    float mi = mask[b * N_ + gi];
    float rD = 1.f / (lv + 1e-16f);
#pragma unroll
    for (int nt = 0; nt < 4; ++nt) {
      size_t off = ((size_t)b * N_ + gi) * D_ + h * DH_ + lm + nt * 16;
      float qv = bf2f(qb[off]);
      O32[off] = mi * (qv + acc[nt][e] * rD);
    }
  }
}

// ---------------------------------------------------------------------------
extern "C" void kernel_launch(void* const* d_in, const int* in_sizes, int n_in,
                              void* d_out, int out_size, void* d_ws, size_t ws_size,
                              hipStream_t stream) {
  const float* Q    = (const float*)d_in[0];
  const float* K    = (const float*)d_in[1];
  const float* U    = (const float*)d_in[2];
  const float* mask = (const float*)d_in[3];
  const float* Wq   = (const float*)d_in[4];
  const float* bq   = (const float*)d_in[5];
  const float* Wk   = (const float*)d_in[6];
  const float* bk   = (const float*)d_in[7];
  const float* Wv   = (const float*)d_in[8];
  const float* bv   = (const float*)d_in[9];
  const float* Wo   = (const float*)d_in[10];
  const float* bo   = (const float*)d_in[11];
  float* out = (float*)d_out;

  char* ws = (char*)d_ws;
  unsigned short* WT   = (unsigned short*)ws;                    // 2 MB (4 mats)
  unsigned short* qb   = (unsigned short*)(ws + (2llu << 20));   // 8 MB
  unsigned short* kb   = (unsigned short*)(ws + (10llu << 20));  // 8 MB
  unsigned short* vtmp = (unsigned short*)(ws + (18llu << 20));  // 8 MB
  unsigned short* vTb  = (unsigned short*)(ws + (26llu << 20));  // 8 MB
  float* O32           = (float*)(ws + (34llu << 20));           // 16 MB -> 50 MB

  prep_w<<<4096, 256, 0, stream>>>(Wq, Wk, Wv, Wo, WT);
  gemm_proj3<<<dim3(256, 3), 256, 0, stream>>>(Q, K, WT, bq, bk, bv, mask, qb, kb, vtmp);
  vtrans_kernel<<<dim3(8, 16, 8), 256, 0, stream>>>(vtmp, vTb);
  attn_kernel<<<512, 512, 0, stream>>>(qb, kb, vTb, U, mask, O32);
  gemm_final<<<256, 256, 0, stream>>>(O32, WT + 3 * 262144, bo, mask, O32, out);
}